// Round 4
// baseline (265.023 us; speedup 1.0000x reference)
//
#include <hip/hip_runtime.h>
#include <hip/hip_bf16.h>

// out[b,j] = sum_{i,k} coef[j,i,k] * tanh(x[b,i])^k
// B=8192, IN=1024, OUT=1024, ORDER=7.
// k=0 plane is a per-j bias (independent of b) -> fold into epilogue.
// Remaining GEMM: M=8192, N=1024, K=IN*7=7168, bf16 MFMA.
// Passes: (1) prep: coef[k>=1] fp32->bf16 + A = tanh-powers(k=1..7) bf16 [8192x7168]
//         (2) bias_k: bias[j] = sum_i coef[j,i,0] (fp32)
//         (3) NT GEMM, m97 structure + XOR-swizzled LDS (0 bank conflicts), + bias.
// Falls back to the round-1 fused kernel if ws too small.

#define BM 128
#define BN 128
#define BK 64
#define KT 7168          // trimmed K = IN * 7
#define KFULL 8192

typedef short bf16x8 __attribute__((ext_vector_type(8)));
typedef short bf16x4 __attribute__((ext_vector_type(4)));
typedef float f32x4  __attribute__((ext_vector_type(4)));

__device__ __forceinline__ unsigned short f2bf(float f) {
    union { float f; unsigned u; } v; v.f = f;
    unsigned r = v.u + 0x7fffu + ((v.u >> 16) & 1u);   // RTE
    return (unsigned short)(r >> 16);
}

__device__ __forceinline__ void gload_lds16(const void* gp, void* lp) {
    __builtin_amdgcn_global_load_lds(
        (const __attribute__((address_space(1))) void*)gp,
        (__attribute__((address_space(3))) void*)lp, 16, 0, 0);
}

// ---- pass 1: prep ----
// cvt branch: group g = 8 (j,i) pairs = 64 floats in, 56 bf16 out (k=1..7 each).
// tanh branch: group g = 8 x values -> 56 bf16 powers out.
#define CVT_BLOCKS  512    // 512*256 threads * 8 pairs  = 1,048,576 pairs
#define TANH_BLOCKS 4096   // 4096*256 threads * 8 xvals = 8,388,608 x

__global__ __launch_bounds__(256)
void prep(const float* __restrict__ x, const float* __restrict__ trp,
          const float* __restrict__ coef, unsigned short* __restrict__ coef_bf,
          unsigned short* __restrict__ A) {
    const int b = blockIdx.x;
    unsigned short tmp[56];
    if (b < CVT_BLOCKS) {
        const size_t g = (size_t)b * 256 + threadIdx.x;
        const float* src = coef + g * 64;
        float buf[64];
        #pragma unroll
        for (int v = 0; v < 16; ++v) {
            const float4 f = *(const float4*)(src + v * 4);
            buf[v*4+0] = f.x; buf[v*4+1] = f.y; buf[v*4+2] = f.z; buf[v*4+3] = f.w;
        }
        #pragma unroll
        for (int p = 0; p < 8; ++p)
            #pragma unroll
            for (int k = 1; k < 8; ++k)
                tmp[p * 7 + k - 1] = f2bf(buf[p * 8 + k]);
        bf16x8* dst = (bf16x8*)(coef_bf + g * 56);
        #pragma unroll
        for (int v = 0; v < 7; ++v) {
            bf16x8 pk;
            #pragma unroll
            for (int s = 0; s < 8; ++s) pk[s] = (short)tmp[v * 8 + s];
            dst[v] = pk;
        }
    } else {
        const size_t g = (size_t)(b - CVT_BLOCKS) * 256 + threadIdx.x;
        const float tr = trp[0];
        const float4 x0 = *(const float4*)(x + g * 8);
        const float4 x1 = *(const float4*)(x + g * 8 + 4);
        const float xs[8] = {x0.x, x0.y, x0.z, x0.w, x1.x, x1.y, x1.z, x1.w};
        #pragma unroll
        for (int p = 0; p < 8; ++p) {
            const float e  = __expf(2.0f * tr * xs[p]);
            const float tt = 1.0f - 2.0f * __builtin_amdgcn_rcpf(e + 1.0f);  // tanh
            float pw = tt;
            #pragma unroll
            for (int k = 1; k < 8; ++k) { tmp[p * 7 + k - 1] = f2bf(pw); pw *= tt; }
        }
        bf16x8* dst = (bf16x8*)(A + g * 56);
        #pragma unroll
        for (int v = 0; v < 7; ++v) {
            bf16x8 pk;
            #pragma unroll
            for (int s = 0; s < 8; ++s) pk[s] = (short)tmp[v * 8 + s];
            dst[v] = pk;
        }
    }
}

// ---- pass 2: bias[j] = sum_i coef[j,i,0], fp32 ----
__global__ __launch_bounds__(256)
void bias_k(const float* __restrict__ coef, float* __restrict__ bias) {
    const int j = blockIdx.x;
    float s = 0.f;
    for (int ii = threadIdx.x; ii < 1024; ii += 256)
        s += coef[(size_t)j * KFULL + (size_t)ii * 8];
    #pragma unroll
    for (int off = 32; off > 0; off >>= 1) s += __shfl_down(s, off, 64);
    __shared__ float ls[4];
    if ((threadIdx.x & 63) == 0) ls[threadIdx.x >> 6] = s;
    __syncthreads();
    if (threadIdx.x == 0) bias[j] = ls[0] + ls[1] + ls[2] + ls[3];
}

// ---- pass 3: NT GEMM (K=7168), m97 structure + XOR swizzle + bias epilogue ----
__global__ __launch_bounds__(256, 2)
void gemm_bt(const unsigned short* __restrict__ A, const unsigned short* __restrict__ Bt,
             const float* __restrict__ bias, float* __restrict__ out)
{
    __shared__ unsigned short As[BM * BK];   // 16 KB
    __shared__ unsigned short Bs[BN * BK];   // 16 KB

    const int t    = threadIdx.x;
    const int m0   = blockIdx.x * BM;
    const int n0   = blockIdx.y * BN;
    const int w    = t >> 6;
    const int lane = t & 63;
    const int wm   = (w >> 1) * 64;
    const int wn   = (w & 1) * 64;
    const int lrow = lane & 15;

    // staging: thread t covers row = r*32 + (t>>3); fetches swizzled chunk
    // (t&7)^((t>>3)&7) so LDS slot s of row m holds global chunk s^(m&7).
    const int srow   = t >> 3;
    const int schunk = (t & 7) ^ (srow & 7);
    const int wbase  = w * 512;

    f32x4 acc[4][4];
    #pragma unroll
    for (int i = 0; i < 4; i++)
        #pragma unroll
        for (int j = 0; j < 4; j++)
            acc[i][j] = (f32x4){0.f, 0.f, 0.f, 0.f};

    const size_t abase = (size_t)(m0 + srow) * KT + schunk * 8;
    const size_t bbase = (size_t)(n0 + srow) * KT + schunk * 8;

    for (int k0 = 0; k0 < KT; k0 += BK) {
        #pragma unroll
        for (int r = 0; r < 4; ++r)
            gload_lds16(A + abase + (size_t)r * 32 * KT + k0, &As[r * 2048 + wbase]);
        #pragma unroll
        for (int r = 0; r < 4; ++r)
            gload_lds16(Bt + bbase + (size_t)r * 32 * KT + k0, &Bs[r * 2048 + wbase]);

        __syncthreads();

        #pragma unroll
        for (int kk = 0; kk < BK; kk += 32) {
            const int soff = ((((kk >> 3) + (lane >> 4)) ^ (lane & 7)) * 8);
            bf16x8 a[4], b[4];
            #pragma unroll
            for (int i = 0; i < 4; i++)
                a[i] = *(const bf16x8*)&As[(wm + i * 16 + lrow) * BK + soff];
            #pragma unroll
            for (int j = 0; j < 4; j++)
                b[j] = *(const bf16x8*)&Bs[(wn + j * 16 + lrow) * BK + soff];
            #pragma unroll
            for (int i = 0; i < 4; i++)
                #pragma unroll
                for (int j = 0; j < 4; j++)
                    acc[i][j] = __builtin_amdgcn_mfma_f32_16x16x32_bf16(a[i], b[j], acc[i][j], 0, 0, 0);
        }

        __syncthreads();
    }

    const int crow = (lane >> 4) * 4;
    const int ccol = lane & 15;
    #pragma unroll
    for (int j = 0; j < 4; j++) {
        const int n = n0 + wn + j * 16 + ccol;
        const float bv = bias[n];
        #pragma unroll
        for (int i = 0; i < 4; i++) {
            const int m = m0 + wm + i * 16 + crow;
            #pragma unroll
            for (int r = 0; r < 4; ++r)
                out[(size_t)(m + r) * 1024 + n] = acc[i][j][r] + bv;
        }
    }
}

// ---- fallback: fused kernel (full K=8192), used only if ws too small ----
#define LDK 72
__global__ __launch_bounds__(256, 2)
void taylor_gemm(const float* __restrict__ x, const float* __restrict__ trp,
                 const float* __restrict__ coef, float* __restrict__ out)
{
    __shared__ unsigned short As[BM * LDK];
    __shared__ unsigned short Bs[BN * LDK];

    const int t  = threadIdx.x;
    const int m0 = blockIdx.x * BM;
    const int n0 = blockIdx.y * BN;
    const float tr = trp[0];

    const int w    = t >> 6;
    const int lane = t & 63;
    const int wm   = (w >> 1) * 64;
    const int wn   = (w & 1) * 64;
    const int lrow = lane & 15;
    const int kq   = (lane >> 4) * 8;

    f32x4 acc[4][4];
    #pragma unroll
    for (int i = 0; i < 4; i++)
        #pragma unroll
        for (int j = 0; j < 4; j++)
            acc[i][j] = (f32x4){0.f, 0.f, 0.f, 0.f};

    const int bcol  = t & 15;
    const int brow0 = t >> 4;
    const int acol  = t & 7;
    const int arow0 = t >> 3;

    for (int k0 = 0; k0 < KFULL; k0 += BK) {
        const int i0 = k0 >> 3;
        #pragma unroll
        for (int r = 0; r < 8; ++r) {
            const int row = brow0 + r * 16;
            const float4 v = *(const float4*)(coef + (size_t)(n0 + row) * KFULL + k0 + bcol * 4);
            bf16x4 pk;
            pk[0] = (short)f2bf(v.x); pk[1] = (short)f2bf(v.y);
            pk[2] = (short)f2bf(v.z); pk[3] = (short)f2bf(v.w);
            *(bf16x4*)&Bs[row * LDK + bcol * 4] = pk;
        }
        #pragma unroll
        for (int r = 0; r < 4; ++r) {
            const int row = arow0 + r * 32;
            const float xv = x[(size_t)(m0 + row) * 1024 + i0 + acol];
            const float e  = __expf(2.0f * tr * xv);
            const float tt = 1.0f - 2.0f / (e + 1.0f);
            bf16x8 pk;
            float p = 1.0f;
            #pragma unroll
            for (int k = 0; k < 8; ++k) { pk[k] = (short)f2bf(p); p *= tt; }
            *(bf16x8*)&As[row * LDK + acol * 8] = pk;
        }
        __syncthreads();
        #pragma unroll
        for (int kk = 0; kk < BK; kk += 32) {
            bf16x8 a[4], b[4];
            #pragma unroll
            for (int i = 0; i < 4; i++)
                a[i] = *(const bf16x8*)&As[(wm + i * 16 + lrow) * LDK + kk + kq];
            #pragma unroll
            for (int j = 0; j < 4; j++)
                b[j] = *(const bf16x8*)&Bs[(wn + j * 16 + lrow) * LDK + kk + kq];
            #pragma unroll
            for (int i = 0; i < 4; i++)
                #pragma unroll
                for (int j = 0; j < 4; j++)
                    acc[i][j] = __builtin_amdgcn_mfma_f32_16x16x32_bf16(a[i], b[j], acc[i][j], 0, 0, 0);
        }
        __syncthreads();
    }

    const int crow = (lane >> 4) * 4;
    const int ccol = lane & 15;
    #pragma unroll
    for (int i = 0; i < 4; i++) {
        #pragma unroll
        for (int j = 0; j < 4; j++) {
            const int m = m0 + wm + i * 16 + crow;
            const int n = n0 + wn + j * 16 + ccol;
            #pragma unroll
            for (int r = 0; r < 4; ++r)
                out[(size_t)(m + r) * 1024 + n] = acc[i][j][r];
        }
    }
}

extern "C" void kernel_launch(void* const* d_in, const int* in_sizes, int n_in,
                              void* d_out, int out_size, void* d_ws, size_t ws_size,
                              hipStream_t stream) {
    const float* x    = (const float*)d_in[0];
    const float* trp  = (const float*)d_in[1];
    const float* coef = (const float*)d_in[2];
    float* out = (float*)d_out;

    const size_t A_BYTES    = (size_t)8192 * KT * 2;   // 117,440,512
    const size_t COEF_BYTES = (size_t)1024 * KT * 2;   //  14,680,064
    const size_t BIAS_BYTES = 1024 * sizeof(float);
    dim3 block(256);

    if (ws_size >= A_BYTES + COEF_BYTES + BIAS_BYTES) {
        unsigned short* A_bf    = (unsigned short*)d_ws;
        unsigned short* coef_bf = (unsigned short*)((char*)d_ws + A_BYTES);
        float*          bias    = (float*)((char*)d_ws + A_BYTES + COEF_BYTES);

        prep<<<dim3(CVT_BLOCKS + TANH_BLOCKS), block, 0, stream>>>(
            x, trp, coef, coef_bf, A_bf);
        bias_k<<<dim3(1024), block, 0, stream>>>(coef, bias);
        gemm_bt<<<dim3(8192 / BM, 1024 / BN), block, 0, stream>>>(
            A_bf, coef_bf, bias, out);
    } else {
        taylor_gemm<<<dim3(8192 / BM, 1024 / BN), block, 0, stream>>>(x, trp, coef, out);
    }
}